// Round 5
// baseline (1737.619 us; speedup 1.0000x reference)
//
#include <hip/hip_runtime.h>
#include <hip/hip_bf16.h>

// MultiAgentGRULoop round 5: two independent recurrence chains per CU.
//   - 512 blocks x 512 thr (8 waves); each block owns 8 batch rows (RB=8),
//     2 blocks/CU -> independent barrier groups fill each other's latency
//     stalls (round 3/4 showed the kernel is dependency-latency-bound:
//     per-SIMD VALU issue ~13%, MFMA ~5%, rest idle).
//   - MFMA M=16 tiles half-padded with zero rows (MFMA util is low; free).
//   - 6 accumulators (r/z split) -> 4-deep MFMA chains instead of 8-deep.
//   - Mask buffer t-major: one ds_read_b128 per cell instead of 4 loads.
//   - __launch_bounds__(512,4) pins VGPR <= 128 so 16 waves/CU fit.

#define T_STEPS 64
#define HID 128
#define NL 3
#define RB 8      // valid batch rows per block
#define MROWS 16  // MFMA M-tile rows (8..15 are zero padding)
#define NTHR 512
#define NBLK 512
#define LSTR 136  // bf16 row stride (shorts): 272 B, 16B-aligned
#define ASTR 132  // f32 act row stride

typedef __attribute__((ext_vector_type(8))) short bf16x8;
typedef __attribute__((ext_vector_type(4))) short short4v;
typedef __attribute__((ext_vector_type(4))) float f32x4;

static __device__ __forceinline__ short f2bf_s(float f) {
  __hip_bfloat16 b = __float2bfloat16(f);
  return __builtin_bit_cast(short, b);
}
__device__ __forceinline__ float sigm(float v) { return 1.f / (1.f + __expf(-v)); }
__device__ __forceinline__ float tanh_f(float v) { return 1.f - 2.f / (__expf(2.f * v) + 1.f); }

__global__ __launch_bounds__(NTHR, 4) void gru5(
    const float* __restrict__ x, const int* __restrict__ invalid,
    const float* __restrict__ w_ih, const float* __restrict__ w_hh,
    const float* __restrict__ b_ih, const float* __restrict__ b_hh,
    float* out)
{
  __shared__ short s_in[2][MROWS * LSTR];   // input bf16 (rows 8..15 always 0)
  __shared__ short s_h[2][MROWS * LSTR];    // h bf16 (rows 8..15 always 0)
  __shared__ float s_act[2][RB * ASTR];     // f32 activation out-staging
  __shared__ int   s_msk[T_STEPS * MROWS];  // mask, t-major (rows 8..15 = 0)

  const int tid = threadIdx.x;
  const int wave = tid >> 6, lane = tid & 63;
  const int lr = lane & 15, lq = lane >> 4;
  const int row_base = (int)blockIdx.x * RB;
  const int srow = tid >> 5, scol = (tid & 31) * 4;  // coalesced f32x4 map

  // ---- mask: transpose to t-major once; pad rows zero ----
  for (int i = tid; i < T_STEPS * MROWS; i += NTHR) {
    const int t = i >> 4, row = i & 15;
    s_msk[i] = (row < RB) ? invalid[(size_t)(row_base + row) * T_STEPS + t] : 0;
  }

  for (int l = 0; l < NL; ++l) {
    // ---- per layer: weights -> bf16 register B-fragments ----
    bf16x8 wI[3][4], wH[3][4];
#pragma unroll
    for (int g = 0; g < 3; ++g)
#pragma unroll
      for (int kf = 0; kf < 4; ++kf) {
        const int wrow = g * HID + wave * 16 + lr;  // B col = lane&15
        const int kofs = kf * 32 + lq * 8;          // k-map identical to A side
        const float* pI = w_ih + ((size_t)l * 3 * HID + wrow) * HID + kofs;
        const float* pH = w_hh + ((size_t)l * 3 * HID + wrow) * HID + kofs;
        float4 a = *(const float4*)pI, b = *(const float4*)(pI + 4);
        float vi[8] = {a.x, a.y, a.z, a.w, b.x, b.y, b.z, b.w};
        float4 c = *(const float4*)pH, d = *(const float4*)(pH + 4);
        float vh[8] = {c.x, c.y, c.z, c.w, d.x, d.y, d.z, d.w};
#pragma unroll
        for (int j = 0; j < 8; ++j) {
          wI[g][kf][j] = f2bf_s(vi[j]);
          wH[g][kf][j] = f2bf_s(vh[j]);
        }
      }
    float bRZ[2], bIn, bHn;  // r,z biases fused; n kept separate
#pragma unroll
    for (int g = 0; g < 2; ++g)
      bRZ[g] = b_ih[l * 3 * HID + g * HID + wave * 16 + lr] +
               b_hh[l * 3 * HID + g * HID + wave * 16 + lr];
    bIn = b_ih[l * 3 * HID + 2 * HID + wave * 16 + lr];
    bHn = b_hh[l * 3 * HID + 2 * HID + wave * 16 + lr];

    // ---- zero h (both bufs) and input pad rows; then stage input[t=0] ----
    for (int i = tid; i < 2 * MROWS * LSTR; i += NTHR) (&s_h[0][0])[i] = 0;
    for (int i = tid; i < 2 * MROWS * LSTR; i += NTHR) (&s_in[0][0])[i] = 0;
    __syncthreads();
    float hprev[4] = {0.f, 0.f, 0.f, 0.f};
    const float* src = (l == 0) ? x : (const float*)out;
    if (srow < RB) {
      float4 v = *(const float4*)(src + ((size_t)(row_base + srow) * T_STEPS + 0) * HID + scol);
      short4v c4 = {f2bf_s(v.x), f2bf_s(v.y), f2bf_s(v.z), f2bf_s(v.w)};
      *(short4v*)&s_in[0][srow * LSTR + scol] = c4;
    }
    __syncthreads();

#pragma unroll 2
    for (int t = 0; t < T_STEPS; ++t) {
      const int p = t & 1;
      // ---- deferred store of step t-1 activations (coalesced) ----
      if (t > 0 && srow < RB) {
        float4 a = *(const float4*)&s_act[p][srow * ASTR + scol];
        *(float4*)(out + ((size_t)(row_base + srow) * T_STEPS + (t - 1)) * HID + scol) = a;
      }
      // ---- prefetch next-step input + this-step mask ----
      float4 pin = make_float4(0.f, 0.f, 0.f, 0.f);
      if (t < T_STEPS - 1 && srow < RB)
        pin = *(const float4*)(src + ((size_t)(row_base + srow) * T_STEPS + (t + 1)) * HID + scol);
      const int4 mk4 = *(const int4*)&s_msk[t * MROWS + lq * 4];
      const int mk[4] = {mk4.x, mk4.y, mk4.z, mk4.w};

      // ---- MFMA phase: 6 accumulators, 4-deep chains ----
      f32x4 aI0 = (f32x4)(bRZ[0]), aH0 = (f32x4)(0.f);
      f32x4 aI1 = (f32x4)(bRZ[1]), aH1 = (f32x4)(0.f);
      f32x4 aN = (f32x4)(bIn), aHn = (f32x4)(bHn);
#pragma unroll
      for (int kf = 0; kf < 4; ++kf) {
        const int ao = lr * LSTR + kf * 32 + lq * 8;  // A row = lane&15
        bf16x8 xh = *(const bf16x8*)&s_in[p][ao];
        bf16x8 hh = *(const bf16x8*)&s_h[p][ao];
        aI0 = __builtin_amdgcn_mfma_f32_16x16x32_bf16(xh, wI[0][kf], aI0, 0, 0, 0);
        aH0 = __builtin_amdgcn_mfma_f32_16x16x32_bf16(hh, wH[0][kf], aH0, 0, 0, 0);
        aI1 = __builtin_amdgcn_mfma_f32_16x16x32_bf16(xh, wI[1][kf], aI1, 0, 0, 0);
        aH1 = __builtin_amdgcn_mfma_f32_16x16x32_bf16(hh, wH[1][kf], aH1, 0, 0, 0);
        aN  = __builtin_amdgcn_mfma_f32_16x16x32_bf16(xh, wI[2][kf], aN, 0, 0, 0);
        aHn = __builtin_amdgcn_mfma_f32_16x16x32_bf16(hh, wH[2][kf], aHn, 0, 0, 0);
      }

      // ---- epilogue: lane owns (rows lq*4+ri, col wave*16+lr); writes [p^1] ----
#pragma unroll
      for (int ri = 0; ri < 4; ++ri) {
        const int row = lq * 4 + ri;
        float rr = sigm(aI0[ri] + aH0[ri]);
        float zz = sigm(aI1[ri] + aH1[ri]);
        float nn = tanh_f(aN[ri] + rr * aHn[ri]);
        float hn = nn + zz * (hprev[ri] - nn);
        float hm = mk[ri] ? 0.f : hn;
        hprev[ri] = hm;
        if (row < RB) {
          // layers 0/1 pass UNMASKED h; final layer emits masked y
          s_act[p ^ 1][row * ASTR + wave * 16 + lr] = (l == NL - 1) ? hm : hn;
          s_h[p ^ 1][row * LSTR + wave * 16 + lr] = f2bf_s(hm);
        }
      }
      if (t < T_STEPS - 1 && srow < RB) {
        short4v c4 = {f2bf_s(pin.x), f2bf_s(pin.y), f2bf_s(pin.z), f2bf_s(pin.w)};
        *(short4v*)&s_in[p ^ 1][srow * LSTR + scol] = c4;
      }
      __syncthreads();  // all [p^1] writes visible, vmcnt drained
    }
    // ---- flush t=63 activations (live in s_act[0]) ----
    if (srow < RB) {
      float4 a = *(const float4*)&s_act[0][srow * ASTR + scol];
      *(float4*)(out + ((size_t)(row_base + srow) * T_STEPS + (T_STEPS - 1)) * HID + scol) = a;
    }
    __syncthreads();  // out-writes drained+visible before next layer stages from out
  }
}

extern "C" void kernel_launch(void* const* d_in, const int* in_sizes, int n_in,
                              void* d_out, int out_size, void* d_ws, size_t ws_size,
                              hipStream_t stream) {
  const float* x       = (const float*)d_in[0];
  const int*   invalid = (const int*)d_in[1];
  const float* w_ih    = (const float*)d_in[2];
  const float* w_hh    = (const float*)d_in[3];
  const float* b_ih    = (const float*)d_in[4];
  const float* b_hh    = (const float*)d_in[5];
  gru5<<<dim3(NBLK), dim3(NTHR), 0, stream>>>(x, invalid, w_ih, w_hh, b_ih, b_hh,
                                              (float*)d_out);
}

// Round 6
// 286.082 us; speedup vs baseline: 6.0739x; 6.0739x over previous
//
#include <hip/hip_runtime.h>
#include <hip/hip_bf16.h>

// MultiAgentGRULoop round 6: raw barrier (no vmcnt drain) + transposed epilogue.
//   - 256 blocks x 512 thr (8 waves); block owns 16 batch rows end-to-end;
//     layer-outer, d_out as inter-layer f32 activation buffer. 1 block/CU,
//     launch_bounds(512,1): R5 showed tighter bounds split the unified
//     VGPR/AGPR file 64/64 and spill the 96-reg weight set (4.6 GB scratch).
//   - OPERAND-SWAPPED MFMA: mfma(W, act) -> D[gate_col][act_row]; lane owns
//     act row (lane&15) x 4 consecutive gate cols (wave*16+lq*4+ri). Epilogue
//     LDS traffic: 1 ds_write_b128 (act) + 1 ds_write_b64 (h bf16) + 1
//     broadcast mask read, replacing 8 scattered writes + 4 scattered reads.
//   - Per-cell sync = s_waitcnt lgkmcnt(0) + raw s_barrier: LDS visibility
//     only; global out-stores/prefetches stay in flight across cells (their
//     only consumer is behind the layer-end __syncthreads()).
//   - h recurrence in f32 registers (exact); bf16 on MFMA paths only.

#define T_STEPS 64
#define HID 128
#define NL 3
#define RB 16
#define NTHR 512
#define NBLK 256
#define LSTR 136   // bf16 row stride (shorts): 272 B, 16B-aligned
#define ASTR 132   // f32 act row stride

typedef __attribute__((ext_vector_type(8))) short bf16x8;
typedef __attribute__((ext_vector_type(4))) short short4v;
typedef __attribute__((ext_vector_type(4))) float f32x4;

static __device__ __forceinline__ short f2bf_s(float f) {
  __hip_bfloat16 b = __float2bfloat16(f);
  return __builtin_bit_cast(short, b);
}
__device__ __forceinline__ float sigm(float v) { return 1.f / (1.f + __expf(-v)); }
__device__ __forceinline__ float tanh_f(float v) { return 1.f - 2.f / (__expf(2.f * v) + 1.f); }

__global__ __launch_bounds__(NTHR, 1) void gru6(
    const float* __restrict__ x, const int* __restrict__ invalid,
    const float* __restrict__ w_ih, const float* __restrict__ w_hh,
    const float* __restrict__ b_ih, const float* __restrict__ b_hh,
    float* out)
{
  __shared__ short s_in[2][RB * LSTR];   // input bf16 (x[t], x[t+1])
  __shared__ short s_h[2][RB * LSTR];    // h bf16 (masked), double-buffered
  __shared__ float s_act[2][RB * ASTR];  // f32 activation out-staging, dbuf
  __shared__ int   s_msk[T_STEPS * RB];  // invalid mask, t-major

  const int tid = threadIdx.x;
  const int wave = tid >> 6, lane = tid & 63;
  const int lr = lane & 15, lq = lane >> 4;
  const int row_base = (int)blockIdx.x * RB;
  const int srow = tid >> 5, scol = (tid & 31) * 4;  // coalesced f32x4 map

  // ---- mask: t-major so per-cell read is one broadcast b32 per lane ----
  for (int i = tid; i < T_STEPS * RB; i += NTHR) {
    const int t = i >> 4, r = i & 15;
    s_msk[i] = invalid[(size_t)(row_base + r) * T_STEPS + t];
  }

  for (int l = 0; l < NL; ++l) {
    // ---- per layer: weights -> bf16 register fragments (A-operand now) ----
    bf16x8 wI[3][4], wH[3][4];
#pragma unroll
    for (int g = 0; g < 3; ++g)
#pragma unroll
      for (int kf = 0; kf < 4; ++kf) {
        const int wrow = g * HID + wave * 16 + lr;  // M row (gate col) = lane&15
        const int kofs = kf * 32 + lq * 8;          // k-map identical both operands
        const float* pI = w_ih + ((size_t)l * 3 * HID + wrow) * HID + kofs;
        const float* pH = w_hh + ((size_t)l * 3 * HID + wrow) * HID + kofs;
        float4 a = *(const float4*)pI, b = *(const float4*)(pI + 4);
        float vi[8] = {a.x, a.y, a.z, a.w, b.x, b.y, b.z, b.w};
        float4 c = *(const float4*)pH, d = *(const float4*)(pH + 4);
        float vh[8] = {c.x, c.y, c.z, c.w, d.x, d.y, d.z, d.w};
#pragma unroll
        for (int j = 0; j < 8; ++j) {
          wI[g][kf][j] = f2bf_s(vi[j]);
          wH[g][kf][j] = f2bf_s(vh[j]);
        }
      }
    // biases per (lq,ri): gate col = wave*16 + lq*4 + ri
    float bRZ0[4], bRZ1[4], bNi[4], bNh[4];
#pragma unroll
    for (int ri = 0; ri < 4; ++ri) {
      const int c = wave * 16 + lq * 4 + ri;
      const size_t base = (size_t)l * 3 * HID;
      bRZ0[ri] = b_ih[base + c] + b_hh[base + c];
      bRZ1[ri] = b_ih[base + HID + c] + b_hh[base + HID + c];
      bNi[ri]  = b_ih[base + 2 * HID + c];
      bNh[ri]  = b_hh[base + 2 * HID + c];
    }

    // ---- h := 0, stage input[t=0] into buffer 0 ----
    for (int i = tid; i < RB * LSTR; i += NTHR) s_h[0][i] = 0;
    float hprev[4] = {0.f, 0.f, 0.f, 0.f};
    const float* src = (l == 0) ? x : (const float*)out;
    {
      float4 v = *(const float4*)(src + ((size_t)(row_base + srow) * T_STEPS + 0) * HID + scol);
      short4v c4 = {f2bf_s(v.x), f2bf_s(v.y), f2bf_s(v.z), f2bf_s(v.w)};
      *(short4v*)&s_in[0][srow * LSTR + scol] = c4;
    }
    __syncthreads();

    for (int t = 0; t < T_STEPS; ++t) {
      const int p = t & 1;
      // ---- deferred store of step t-1 activations (stays in flight) ----
      if (t > 0) {
        float4 a = *(const float4*)&s_act[p][srow * ASTR + scol];
        *(float4*)(out + ((size_t)(row_base + srow) * T_STEPS + (t - 1)) * HID + scol) = a;
      }
      // ---- prefetch next-step input + this-step mask (broadcast read) ----
      float4 pin = make_float4(0.f, 0.f, 0.f, 0.f);
      if (t < T_STEPS - 1)
        pin = *(const float4*)(src + ((size_t)(row_base + srow) * T_STEPS + (t + 1)) * HID + scol);
      const int mk = s_msk[t * RB + lr];  // lane's act row

      // ---- MFMA phase, swapped operands: D[gate_col][act_row] ----
      f32x4 aI0 = {bRZ0[0], bRZ0[1], bRZ0[2], bRZ0[3]};
      f32x4 aH0 = (f32x4)(0.f);
      f32x4 aI1 = {bRZ1[0], bRZ1[1], bRZ1[2], bRZ1[3]};
      f32x4 aH1 = (f32x4)(0.f);
      f32x4 aN  = {bNi[0], bNi[1], bNi[2], bNi[3]};
      f32x4 aHn = {bNh[0], bNh[1], bNh[2], bNh[3]};
#pragma unroll
      for (int kf = 0; kf < 4; ++kf) {
        const int ao = lr * LSTR + kf * 32 + lq * 8;  // act row = lane&15
        bf16x8 xh = *(const bf16x8*)&s_in[p][ao];
        bf16x8 hh = *(const bf16x8*)&s_h[p][ao];
        aI0 = __builtin_amdgcn_mfma_f32_16x16x32_bf16(wI[0][kf], xh, aI0, 0, 0, 0);
        aH0 = __builtin_amdgcn_mfma_f32_16x16x32_bf16(wH[0][kf], hh, aH0, 0, 0, 0);
        aI1 = __builtin_amdgcn_mfma_f32_16x16x32_bf16(wI[1][kf], xh, aI1, 0, 0, 0);
        aH1 = __builtin_amdgcn_mfma_f32_16x16x32_bf16(wH[1][kf], hh, aH1, 0, 0, 0);
        aN  = __builtin_amdgcn_mfma_f32_16x16x32_bf16(wI[2][kf], xh, aN, 0, 0, 0);
        aHn = __builtin_amdgcn_mfma_f32_16x16x32_bf16(wH[2][kf], hh, aHn, 0, 0, 0);
      }

      // ---- epilogue: lane owns act row lr, gate cols wave*16+lq*4+{0..3} ----
      float4 actv;
      short4v hb;
#pragma unroll
      for (int ri = 0; ri < 4; ++ri) {
        float rr = sigm(aI0[ri] + aH0[ri]);
        float zz = sigm(aI1[ri] + aH1[ri]);
        float nn = tanh_f(aN[ri] + rr * aHn[ri]);
        float hn = nn + zz * (hprev[ri] - nn);
        float hm = mk ? 0.f : hn;
        hprev[ri] = hm;
        ((float*)&actv)[ri] = (l == NL - 1) ? hm : hn;  // y masked, inter-layer unmasked
        hb[ri] = f2bf_s(hm);
      }
      {
        const int cb = wave * 16 + lq * 4;
        *(float4*)&s_act[p ^ 1][lr * ASTR + cb] = actv;   // one b128
        *(short4v*)&s_h[p ^ 1][lr * LSTR + cb] = hb;      // one b64
      }
      if (t < T_STEPS - 1) {
        short4v c4 = {f2bf_s(pin.x), f2bf_s(pin.y), f2bf_s(pin.z), f2bf_s(pin.w)};
        *(short4v*)&s_in[p ^ 1][srow * LSTR + scol] = c4;
      }
      // ---- LDS-only sync: no vmcnt drain; globals stay in flight ----
      asm volatile("s_waitcnt lgkmcnt(0)" ::: "memory");
      __builtin_amdgcn_s_barrier();
    }
    // ---- flush t=63 activations (live in s_act[0]) ----
    {
      float4 a = *(const float4*)&s_act[0][srow * ASTR + scol];
      *(float4*)(out + ((size_t)(row_base + srow) * T_STEPS + (T_STEPS - 1)) * HID + scol) = a;
    }
    __syncthreads();  // full drain: out-writes visible before next layer reads out
  }
}

extern "C" void kernel_launch(void* const* d_in, const int* in_sizes, int n_in,
                              void* d_out, int out_size, void* d_ws, size_t ws_size,
                              hipStream_t stream) {
  const float* x       = (const float*)d_in[0];
  const int*   invalid = (const int*)d_in[1];
  const float* w_ih    = (const float*)d_in[2];
  const float* w_hh    = (const float*)d_in[3];
  const float* b_ih    = (const float*)d_in[4];
  const float* b_hh    = (const float*)d_in[5];
  gru6<<<dim3(NBLK), dim3(NTHR), 0, stream>>>(x, invalid, w_ih, w_hh, b_ih, b_hh,
                                              (float*)d_out);
}